// Round 1
// baseline (371.412 us; speedup 1.0000x reference)
//
#include <hip/hip_runtime.h>

typedef __bf16 bf16_t;
typedef __bf16 bf16x4 __attribute__((ext_vector_type(4)));
typedef __bf16 bf16x8 __attribute__((ext_vector_type(8)));
typedef float  f32x4  __attribute__((ext_vector_type(4)));

// B=4, S=1024, D=1024, H=16, HD=64
// MFMA 16x16x32 bf16 layouts (verified per guide m89/m91):
//   A-frag: row = lane&15, k = (lane>>4)*8 + j   (one contiguous 16B read)
//   B-frag: col = lane&15, k = (lane>>4)*8 + j   (contiguous read from B^T rows)
//   C/D:    col = lane&15, row = (lane>>4)*4 + reg

__device__ __forceinline__ void gload16(const bf16_t* g, bf16_t* l) {
  __builtin_amdgcn_global_load_lds((const __attribute__((address_space(1))) void*)g,
                                   (__attribute__((address_space(3))) void*)l, 16, 0, 0);
}

// ---------------- fp32 -> bf16 elementwise ----------------
__global__ __launch_bounds__(256) void k_cvt_bf16(const float* __restrict__ in,
                                                  bf16_t* __restrict__ out) {
  int i = (blockIdx.x * 256 + threadIdx.x) * 4;
  const float4 v = *reinterpret_cast<const float4*>(in + i);
  bf16x4 o = { (bf16_t)v.x, (bf16_t)v.y, (bf16_t)v.z, (bf16_t)v.w };
  *reinterpret_cast<bf16x4*>(out + i) = o;
}

// ---------------- transpose + cvt: WT[n][k] = W[k][n], 1024x1024 ----------------
__global__ __launch_bounds__(256) void k_transpose_cvt(const float* __restrict__ W,
                                                       bf16_t* __restrict__ WT) {
  __shared__ float t[32][33];
  int bx = blockIdx.x & 31, by = blockIdx.x >> 5;
  int lx = threadIdx.x & 31, ly = threadIdx.x >> 5;  // 32 x 8
#pragma unroll
  for (int i = 0; i < 32; i += 8)
    t[ly + i][lx] = W[(size_t)(by * 32 + ly + i) * 1024 + bx * 32 + lx];
  __syncthreads();
#pragma unroll
  for (int i = 0; i < 32; i += 8)
    WT[(size_t)(bx * 32 + ly + i) * 1024 + by * 32 + lx] = (bf16_t)t[lx][ly + i];
}

// ---------------- content bias: cb[b,h,s] = sum_k x[b,s,k]*Wb[k,h] (full fp32) ----------------
__global__ __launch_bounds__(256) void k_cbias(const float* __restrict__ x,
                                               const float* __restrict__ Wb,
                                               float* __restrict__ cb) {
  int row = blockIdx.x;  // b*1024 + s
  int t = threadIdx.x;
  int h = t & 15, part = t >> 4;  // 16 heads x 16 k-parts of 64
  const float* xr = x + (size_t)row * 1024 + part * 64;
  const float* wb = Wb + (size_t)part * 64 * 16 + h;
  float s = 0.f;
#pragma unroll 8
  for (int i = 0; i < 64; ++i) s += xr[i] * wb[i * 16];
  __shared__ float ps[16][17];
  ps[part][h] = s;
  __syncthreads();
  if (t < 16) {
    float v = 0.f;
#pragma unroll
    for (int p = 0; p < 16; ++p) v += ps[p][t];
    cb[((size_t)(row >> 10) * 16 + t) * 1024 + (row & 1023)] = v;
  }
}

// ---------------- 128x128-tile bf16 GEMM, K=1024, m97 structure ----------------
// EPI 0: Q  -> *mixing[h,d]*0.125, write bf16 [b,h,s,d]
// EPI 1: K  -> write bf16 [b,h,s,d]
// EPI 2: V  -> write bf16 transposed [b,h,d,s]
// EPI 3: out-> fp32 row-major + bd[col]
template <int EPI>
__global__ __launch_bounds__(256) void k_gemm128(const bf16_t* __restrict__ A,
                                                 const bf16_t* __restrict__ BT,
                                                 const float* __restrict__ aux,
                                                 void* __restrict__ outp) {
  constexpr int K = 1024;
  const int tid = threadIdx.x;
  const int w = tid >> 6, lane = tid & 63;
  const int r = lane & 15, g = lane >> 4;
  const int nb = blockIdx.x & 7;   // N/128 = 8
  const int mb = blockIdx.x >> 3;  // M/128

  __shared__ bf16_t As[128 * 32];
  __shared__ bf16_t Bs[128 * 32];

  f32x4 acc[4][4] = {};

  const bf16_t* Ag = A + (size_t)(mb * 128 + w * 32 + (lane >> 2)) * K + (lane & 3) * 8;
  const bf16_t* Bg = BT + (size_t)(nb * 128 + w * 32 + (lane >> 2)) * K + (lane & 3) * 8;
  bf16_t* Asw = As + (w * 32) * 32;  // wave-uniform LDS dest base
  bf16_t* Bsw = Bs + (w * 32) * 32;

  const int mrow0 = (w >> 1) * 64, ncol0 = (w & 1) * 64;

  for (int k0 = 0; k0 < K; k0 += 32) {
    gload16(Ag + k0, Asw);
    gload16(Ag + 16 * K + k0, Asw + 16 * 32);
    gload16(Bg + k0, Bsw);
    gload16(Bg + 16 * K + k0, Bsw + 16 * 32);
    asm volatile("s_waitcnt vmcnt(0)" ::: "memory");
    __syncthreads();

    bf16x8 av[4], bv[4];
#pragma unroll
    for (int mi = 0; mi < 4; ++mi)
      av[mi] = *reinterpret_cast<const bf16x8*>(As + (mrow0 + mi * 16 + r) * 32 + g * 8);
#pragma unroll
    for (int ni = 0; ni < 4; ++ni)
      bv[ni] = *reinterpret_cast<const bf16x8*>(Bs + (ncol0 + ni * 16 + r) * 32 + g * 8);
#pragma unroll
    for (int mi = 0; mi < 4; ++mi)
#pragma unroll
      for (int ni = 0; ni < 4; ++ni)
        acc[mi][ni] = __builtin_amdgcn_mfma_f32_16x16x32_bf16(av[mi], bv[ni], acc[mi][ni], 0, 0, 0);
    __syncthreads();
  }

  const int row0 = mb * 128 + mrow0, col0 = nb * 128 + ncol0;
#pragma unroll
  for (int mi = 0; mi < 4; ++mi)
#pragma unroll
    for (int ni = 0; ni < 4; ++ni)
#pragma unroll
      for (int rr = 0; rr < 4; ++rr) {
        int row = row0 + mi * 16 + g * 4 + rr;
        int col = col0 + ni * 16 + r;
        float v = acc[mi][ni][rr];
        if constexpr (EPI == 0) {
          int h = col >> 6, dd = col & 63;
          v *= aux[h * 64 + dd] * 0.125f;  // mixing, and fold 1/sqrt(64)
          ((bf16_t*)outp)[(((size_t)(row >> 10) * 16 + h) * 1024 + (row & 1023)) * 64 + dd] = (bf16_t)v;
        } else if constexpr (EPI == 1) {
          int h = col >> 6, dd = col & 63;
          ((bf16_t*)outp)[(((size_t)(row >> 10) * 16 + h) * 1024 + (row & 1023)) * 64 + dd] = (bf16_t)v;
        } else if constexpr (EPI == 2) {
          int h = col >> 6, dd = col & 63;
          ((bf16_t*)outp)[(((size_t)(row >> 10) * 16 + h) * 64 + dd) * 1024 + (row & 1023)] = (bf16_t)v;
        } else {
          ((float*)outp)[(size_t)row * 1024 + col] = v + aux[col];
        }
      }
}

// ---------------- scores + bias + mask + softmax -> P (fp32, to d_out) ----------------
// block: one (b,h), 16 q rows; 4 waves, wave w owns keys [w*256, w*256+256)
__global__ __launch_bounds__(256) void k_attn_softmax(const bf16_t* __restrict__ Qm,
                                                      const bf16_t* __restrict__ Kw,
                                                      const float* __restrict__ cb,
                                                      const float* __restrict__ mask,
                                                      float* __restrict__ P) {
  const int tid = threadIdx.x;
  const int w = tid >> 6, lane = tid & 63;
  const int r = lane & 15, g = lane >> 4;
  const int qt = blockIdx.x & 63;
  const int bh = blockIdx.x >> 6;
  const int b = bh >> 4;
  const int q0 = qt * 16;

  __shared__ float cbm[1024];
  __shared__ float red[2][16][4];

  for (int i = tid; i < 1024; i += 256)
    cbm[i] = cb[(size_t)bh * 1024 + i] + mask[b * 1024 + i];

  const bf16_t* qb = Qm + ((size_t)bh * 1024 + q0) * 64;
  bf16x8 aq0 = *reinterpret_cast<const bf16x8*>(qb + r * 64 + g * 8);
  bf16x8 aq1 = *reinterpret_cast<const bf16x8*>(qb + r * 64 + 32 + g * 8);
  __syncthreads();

  const bf16_t* kb = Kw + ((size_t)bh * 1024 + w * 256) * 64;
  f32x4 acc[16];
#pragma unroll
  for (int t = 0; t < 16; ++t) {
    bf16x8 b0 = *reinterpret_cast<const bf16x8*>(kb + (t * 16 + r) * 64 + g * 8);
    bf16x8 b1 = *reinterpret_cast<const bf16x8*>(kb + (t * 16 + r) * 64 + 32 + g * 8);
    f32x4 c = {0.f, 0.f, 0.f, 0.f};
    c = __builtin_amdgcn_mfma_f32_16x16x32_bf16(aq0, b0, c, 0, 0, 0);
    c = __builtin_amdgcn_mfma_f32_16x16x32_bf16(aq1, b1, c, 0, 0, 0);
    acc[t] = c;
  }

  // add per-key bias, track row max (row = g*4+rr held across lanes r=0..15 and tiles t)
  float mx[4] = {-1e30f, -1e30f, -1e30f, -1e30f};
#pragma unroll
  for (int t = 0; t < 16; ++t)
#pragma unroll
    for (int rr = 0; rr < 4; ++rr) {
      float s = acc[t][rr] + cbm[w * 256 + t * 16 + r];
      acc[t][rr] = s;
      mx[rr] = fmaxf(mx[rr], s);
    }
#pragma unroll
  for (int m_ = 1; m_ <= 8; m_ <<= 1)
#pragma unroll
    for (int rr = 0; rr < 4; ++rr)
      mx[rr] = fmaxf(mx[rr], __shfl_xor(mx[rr], m_));
  if (r == 0) {
#pragma unroll
    for (int rr = 0; rr < 4; ++rr) red[0][g * 4 + rr][w] = mx[rr];
  }
  __syncthreads();
  float m4[4];
#pragma unroll
  for (int rr = 0; rr < 4; ++rr) {
    float v = fmaxf(fmaxf(red[0][g * 4 + rr][0], red[0][g * 4 + rr][1]),
                    fmaxf(red[0][g * 4 + rr][2], red[0][g * 4 + rr][3]));
    m4[rr] = v;
  }
  float sm[4] = {0.f, 0.f, 0.f, 0.f};
#pragma unroll
  for (int t = 0; t < 16; ++t)
#pragma unroll
    for (int rr = 0; rr < 4; ++rr) {
      float p = __expf(acc[t][rr] - m4[rr]);
      acc[t][rr] = p;
      sm[rr] += p;
    }
#pragma unroll
  for (int m_ = 1; m_ <= 8; m_ <<= 1)
#pragma unroll
    for (int rr = 0; rr < 4; ++rr)
      sm[rr] += __shfl_xor(sm[rr], m_);
  if (r == 0) {
#pragma unroll
    for (int rr = 0; rr < 4; ++rr) red[1][g * 4 + rr][w] = sm[rr];
  }
  __syncthreads();
  float l4[4];
#pragma unroll
  for (int rr = 0; rr < 4; ++rr)
    l4[rr] = 1.f / (red[1][g * 4 + rr][0] + red[1][g * 4 + rr][1] +
                    red[1][g * 4 + rr][2] + red[1][g * 4 + rr][3]);

  float* pb = P + ((size_t)bh * 1024 + q0) * 1024 + w * 256;
#pragma unroll
  for (int t = 0; t < 16; ++t)
#pragma unroll
    for (int rr = 0; rr < 4; ++rr)
      pb[(size_t)(g * 4 + rr) * 1024 + t * 16 + r] = acc[t][rr] * l4[rr];
}

// ---------------- PV: aout[b,s,(h,hd)] = P @ V (P fp32 from d_out, V^T bf16) ----------------
__global__ __launch_bounds__(256) void k_pv(const float* __restrict__ P,
                                            const bf16_t* __restrict__ VT,
                                            bf16_t* __restrict__ aout) {
  const int tid = threadIdx.x;
  const int w = tid >> 6, lane = tid & 63;
  const int r = lane & 15, g = lane >> 4;
  const int qt = blockIdx.x & 15;  // 16 blocks of 64 q-rows per (b,h)
  const int bh = blockIdx.x >> 4;
  const int b = bh >> 4, h = bh & 15;
  const int q0 = qt * 64 + w * 16;

  f32x4 acc[4] = {};
  const float* pr = P + ((size_t)bh * 1024 + q0 + r) * 1024 + g * 8;
  const bf16_t* vb = VT + (size_t)bh * 64 * 1024 + g * 8;
#pragma unroll 4
  for (int kb = 0; kb < 32; ++kb) {
    float4 lo = *reinterpret_cast<const float4*>(pr + kb * 32);
    float4 hi = *reinterpret_cast<const float4*>(pr + kb * 32 + 4);
    bf16x8 a;
    a[0] = (bf16_t)lo.x; a[1] = (bf16_t)lo.y; a[2] = (bf16_t)lo.z; a[3] = (bf16_t)lo.w;
    a[4] = (bf16_t)hi.x; a[5] = (bf16_t)hi.y; a[6] = (bf16_t)hi.z; a[7] = (bf16_t)hi.w;
#pragma unroll
    for (int nt = 0; nt < 4; ++nt) {
      bf16x8 bvv = *reinterpret_cast<const bf16x8*>(vb + (size_t)(nt * 16 + r) * 1024 + kb * 32);
      acc[nt] = __builtin_amdgcn_mfma_f32_16x16x32_bf16(a, bvv, acc[nt], 0, 0, 0);
    }
  }
#pragma unroll
  for (int nt = 0; nt < 4; ++nt)
#pragma unroll
    for (int rr = 0; rr < 4; ++rr)
      aout[((size_t)b * 1024 + q0 + g * 4 + rr) * 1024 + h * 64 + nt * 16 + r] =
          (bf16_t)acc[nt][rr];
}

extern "C" void kernel_launch(void* const* d_in, const int* in_sizes, int n_in,
                              void* d_out, int out_size, void* d_ws, size_t ws_size,
                              hipStream_t stream) {
  const float* x      = (const float*)d_in[0];
  const float* mask   = (const float*)d_in[1];
  const float* Wq     = (const float*)d_in[2];
  const float* Wk     = (const float*)d_in[3];
  const float* Wv     = (const float*)d_in[4];
  const float* Wb     = (const float*)d_in[5];
  const float* mixing = (const float*)d_in[6];
  const float* Wd     = (const float*)d_in[7];
  const float* bd     = (const float*)d_in[8];

  char* ws = (char*)d_ws;
  bf16_t* xb   = (bf16_t*)(ws + 0);         //  8,388,608
  bf16_t* WqT  = (bf16_t*)(ws + 8388608);   //  2,097,152
  bf16_t* WkT  = (bf16_t*)(ws + 10485760);  //  2,097,152
  bf16_t* WvT  = (bf16_t*)(ws + 12582912);  //  2,097,152
  bf16_t* WdT  = (bf16_t*)(ws + 14680064);  //  2,097,152
  bf16_t* Qm   = (bf16_t*)(ws + 16777216);  //  8,388,608  [b,h,s,d] * mixing/8
  bf16_t* Kw   = (bf16_t*)(ws + 25165824);  //  8,388,608  [b,h,s,d]
  bf16_t* VT   = (bf16_t*)(ws + 33554432);  //  8,388,608  [b,h,d,s]
  bf16_t* aout = (bf16_t*)(ws + 41943040);  //  8,388,608  [b,s,(h,hd)]
  float*  cb   = (float*)(ws + 50331648);   //    262,144  [b,h,s]
  if (ws_size < 50593792) return;

  float* outO = (float*)d_out;        // attn_output [4,1024,1024]
  float* outP = outO + 4194304;       // attn_weights [4,16,1024,1024]

  k_cvt_bf16<<<4096, 256, 0, stream>>>(x, xb);
  k_transpose_cvt<<<1024, 256, 0, stream>>>(Wq, WqT);
  k_transpose_cvt<<<1024, 256, 0, stream>>>(Wk, WkT);
  k_transpose_cvt<<<1024, 256, 0, stream>>>(Wv, WvT);
  k_transpose_cvt<<<1024, 256, 0, stream>>>(Wd, WdT);
  k_cbias<<<4096, 256, 0, stream>>>(x, Wb, cb);
  k_gemm128<0><<<256, 256, 0, stream>>>(xb, WqT, mixing, (void*)Qm);
  k_gemm128<1><<<256, 256, 0, stream>>>(xb, WkT, nullptr, (void*)Kw);
  k_gemm128<2><<<256, 256, 0, stream>>>(xb, WvT, nullptr, (void*)VT);
  k_attn_softmax<<<4096, 256, 0, stream>>>(Qm, Kw, cb, mask, outP);
  k_pv<<<1024, 256, 0, stream>>>(outP, VT, aout);
  k_gemm128<3><<<256, 256, 0, stream>>>(aout, WdT, bd, (void*)outO);
}

// Round 2
// 268.439 us; speedup vs baseline: 1.3836x; 1.3836x over previous
//
#include <hip/hip_runtime.h>

typedef __bf16 bf16_t;
typedef __bf16 bf16x4 __attribute__((ext_vector_type(4)));
typedef __bf16 bf16x8 __attribute__((ext_vector_type(8)));
typedef float  f32x4  __attribute__((ext_vector_type(4)));

// B=4, S=1024, D=1024, H=16, HD=64
// MFMA 16x16x32 bf16 layouts (m89/m91):
//   A-frag: row = lane&15, k = (lane>>4)*8 + j
//   B-frag: col = lane&15, k = (lane>>4)*8 + j  (from B^T rows)
//   C/D:    col = lane&15, row = (lane>>4)*4 + reg

__device__ __forceinline__ void gload16(const bf16_t* g, bf16_t* l) {
  __builtin_amdgcn_global_load_lds((const __attribute__((address_space(1))) void*)g,
                                   (__attribute__((address_space(3))) void*)l, 16, 0, 0);
}

// ---------------- fp32 -> bf16 elementwise ----------------
__global__ __launch_bounds__(256) void k_cvt_bf16(const float* __restrict__ in,
                                                  bf16_t* __restrict__ out) {
  int i = (blockIdx.x * 256 + threadIdx.x) * 4;
  const float4 v = *reinterpret_cast<const float4*>(in + i);
  bf16x4 o = { (bf16_t)v.x, (bf16_t)v.y, (bf16_t)v.z, (bf16_t)v.w };
  *reinterpret_cast<bf16x4*>(out + i) = o;
}

// ---------------- batched transpose + cvt: WT[n][k] = W[k][n], 4x 1024x1024 ----------------
__global__ __launch_bounds__(256) void k_transpose_cvt4(
    const float* __restrict__ W0, const float* __restrict__ W1,
    const float* __restrict__ W2, const float* __restrict__ W3,
    bf16_t* __restrict__ T0, bf16_t* __restrict__ T1,
    bf16_t* __restrict__ T2, bf16_t* __restrict__ T3) {
  const float* W; bf16_t* WT;
  switch (blockIdx.y) {
    case 0: W = W0; WT = T0; break;
    case 1: W = W1; WT = T1; break;
    case 2: W = W2; WT = T2; break;
    default: W = W3; WT = T3; break;
  }
  __shared__ float t[32][33];
  int bx = blockIdx.x & 31, by = blockIdx.x >> 5;
  int lx = threadIdx.x & 31, ly = threadIdx.x >> 5;  // 32 x 8
#pragma unroll
  for (int i = 0; i < 32; i += 8)
    t[ly + i][lx] = W[(size_t)(by * 32 + ly + i) * 1024 + bx * 32 + lx];
  __syncthreads();
#pragma unroll
  for (int i = 0; i < 32; i += 8)
    WT[(size_t)(bx * 32 + ly + i) * 1024 + by * 32 + lx] = (bf16_t)t[lx][ly + i];
}

// ---------------- content bias: cb[b,h,s] = sum_k x[b,s,k]*Wb[k,h] (full fp32) ----------------
__global__ __launch_bounds__(256) void k_cbias(const float* __restrict__ x,
                                               const float* __restrict__ Wb,
                                               float* __restrict__ cb) {
  int row = blockIdx.x;  // b*1024 + s
  int t = threadIdx.x;
  int h = t & 15, part = t >> 4;  // 16 heads x 16 k-parts of 64
  const float* xr = x + (size_t)row * 1024 + part * 64;
  const float* wb = Wb + (size_t)part * 64 * 16 + h;
  float s = 0.f;
#pragma unroll 8
  for (int i = 0; i < 64; ++i) s += xr[i] * wb[i * 16];
  __shared__ float ps[16][17];
  ps[part][h] = s;
  __syncthreads();
  if (t < 16) {
    float v = 0.f;
#pragma unroll
    for (int p = 0; p < 16; ++p) v += ps[p][t];
    cb[((size_t)(row >> 10) * 16 + t) * 1024 + (row & 1023)] = v;
  }
}

// ---------------- 128x128-tile bf16 GEMM, K=1024, m97 structure ----------------
// EPI 0: fused QKV (N=3072): nb 0..7 -> Q (*mixing/8, [b,h,s,d]),
//                            nb 8..15 -> K ([b,h,s,d]), nb 16..23 -> V^T ([b,h,d,s])
// EPI 1: dense (N=1024): fp32 + bd[col]
template <int EPI, int NB>
__global__ __launch_bounds__(256) void k_gemm128(const bf16_t* __restrict__ A,
                                                 const bf16_t* __restrict__ BT,
                                                 const float* __restrict__ aux,
                                                 bf16_t* __restrict__ o0,
                                                 bf16_t* __restrict__ o1,
                                                 bf16_t* __restrict__ o2,
                                                 float* __restrict__ of) {
  constexpr int K = 1024;
  const int tid = threadIdx.x;
  const int w = tid >> 6, lane = tid & 63;
  const int r = lane & 15, g = lane >> 4;
  const int nb = blockIdx.x % NB;
  const int mb = blockIdx.x / NB;

  __shared__ bf16_t As[128 * 32];
  __shared__ bf16_t Bs[128 * 32];

  f32x4 acc[4][4] = {};

  const bf16_t* Ag = A + (size_t)(mb * 128 + w * 32 + (lane >> 2)) * K + (lane & 3) * 8;
  const bf16_t* Bg = BT + (size_t)(nb * 128 + w * 32 + (lane >> 2)) * K + (lane & 3) * 8;
  bf16_t* Asw = As + (w * 32) * 32;  // wave-uniform LDS dest base
  bf16_t* Bsw = Bs + (w * 32) * 32;

  const int mrow0 = (w >> 1) * 64, ncol0 = (w & 1) * 64;

  for (int k0 = 0; k0 < K; k0 += 32) {
    gload16(Ag + k0, Asw);
    gload16(Ag + 16 * K + k0, Asw + 16 * 32);
    gload16(Bg + k0, Bsw);
    gload16(Bg + 16 * K + k0, Bsw + 16 * 32);
    asm volatile("s_waitcnt vmcnt(0)" ::: "memory");
    __syncthreads();

    bf16x8 av[4], bv[4];
#pragma unroll
    for (int mi = 0; mi < 4; ++mi)
      av[mi] = *reinterpret_cast<const bf16x8*>(As + (mrow0 + mi * 16 + r) * 32 + g * 8);
#pragma unroll
    for (int ni = 0; ni < 4; ++ni)
      bv[ni] = *reinterpret_cast<const bf16x8*>(Bs + (ncol0 + ni * 16 + r) * 32 + g * 8);
#pragma unroll
    for (int mi = 0; mi < 4; ++mi)
#pragma unroll
      for (int ni = 0; ni < 4; ++ni)
        acc[mi][ni] = __builtin_amdgcn_mfma_f32_16x16x32_bf16(av[mi], bv[ni], acc[mi][ni], 0, 0, 0);
    __syncthreads();
  }

  const int row0 = mb * 128 + mrow0;
  if constexpr (EPI == 0) {
    const int matk = nb >> 3;
    const int col0 = (nb & 7) * 128 + ncol0;
#pragma unroll
    for (int mi = 0; mi < 4; ++mi)
#pragma unroll
      for (int ni = 0; ni < 4; ++ni)
#pragma unroll
        for (int rr = 0; rr < 4; ++rr) {
          int row = row0 + mi * 16 + g * 4 + rr;
          int col = col0 + ni * 16 + r;
          int h = col >> 6, dd = col & 63;
          size_t bh_ = (size_t)(row >> 10) * 16 + h;
          float v = acc[mi][ni][rr];
          if (matk == 0) {
            v *= aux[col] * 0.125f;  // mixing[h,dd] flat == col; fold 1/sqrt(64)
            o0[(bh_ * 1024 + (row & 1023)) * 64 + dd] = (bf16_t)v;
          } else if (matk == 1) {
            o1[(bh_ * 1024 + (row & 1023)) * 64 + dd] = (bf16_t)v;
          } else {
            o2[(bh_ * 64 + dd) * 1024 + (row & 1023)] = (bf16_t)v;
          }
        }
  } else {
    const int col0 = nb * 128 + ncol0;
#pragma unroll
    for (int mi = 0; mi < 4; ++mi)
#pragma unroll
      for (int ni = 0; ni < 4; ++ni)
#pragma unroll
        for (int rr = 0; rr < 4; ++rr) {
          int row = row0 + mi * 16 + g * 4 + rr;
          int col = col0 + ni * 16 + r;
          of[(size_t)row * 1024 + col] = acc[mi][ni][rr] + aux[col];
        }
  }
}

// ---------------- fused: scores + bias + mask + softmax -> P (fp32 d_out) ; PV -> aout ----------------
// block: one (b,h), 16 q rows; 4 waves. Phase 1: wave w owns keys [w*256, w*256+256).
// P stripe kept in LDS as bf16 (A-frag layout). Phase 2: wave w owns d-cols [w*16, w*16+16).
__global__ __launch_bounds__(256) void k_attn_fused(const bf16_t* __restrict__ Qm,
                                                    const bf16_t* __restrict__ Kw,
                                                    const bf16_t* __restrict__ VT,
                                                    const float* __restrict__ cb,
                                                    const float* __restrict__ mask,
                                                    float* __restrict__ P,
                                                    bf16_t* __restrict__ aout) {
  const int tid = threadIdx.x;
  const int w = tid >> 6, lane = tid & 63;
  const int r = lane & 15, g = lane >> 4;
  const int qt = blockIdx.x & 63;
  const int bh = blockIdx.x >> 6;
  const int b = bh >> 4, h = bh & 15;
  const int q0 = qt * 16;

  constexpr int PSTR = 1032;  // pad 8 bf16: row stride 516 dwords -> banks spread
  __shared__ float cbm[1024];
  __shared__ float red[2][16][4];
  __shared__ bf16_t Plds[16 * PSTR];  // 33 KB

  for (int i = tid; i < 1024; i += 256)
    cbm[i] = cb[(size_t)bh * 1024 + i] + mask[b * 1024 + i];

  const bf16_t* qb = Qm + ((size_t)bh * 1024 + q0) * 64;
  bf16x8 aq0 = *reinterpret_cast<const bf16x8*>(qb + r * 64 + g * 8);
  bf16x8 aq1 = *reinterpret_cast<const bf16x8*>(qb + r * 64 + 32 + g * 8);
  __syncthreads();

  const bf16_t* kb = Kw + ((size_t)bh * 1024 + w * 256) * 64;
  f32x4 acc[16];
#pragma unroll
  for (int t = 0; t < 16; ++t) {
    bf16x8 b0 = *reinterpret_cast<const bf16x8*>(kb + (t * 16 + r) * 64 + g * 8);
    bf16x8 b1 = *reinterpret_cast<const bf16x8*>(kb + (t * 16 + r) * 64 + 32 + g * 8);
    f32x4 c = {0.f, 0.f, 0.f, 0.f};
    c = __builtin_amdgcn_mfma_f32_16x16x32_bf16(aq0, b0, c, 0, 0, 0);
    c = __builtin_amdgcn_mfma_f32_16x16x32_bf16(aq1, b1, c, 0, 0, 0);
    acc[t] = c;
  }

  // add per-key bias+mask, row max over this wave's 256 keys
  float mx[4] = {-1e30f, -1e30f, -1e30f, -1e30f};
#pragma unroll
  for (int t = 0; t < 16; ++t)
#pragma unroll
    for (int rr = 0; rr < 4; ++rr) {
      float s = acc[t][rr] + cbm[w * 256 + t * 16 + r];
      acc[t][rr] = s;
      mx[rr] = fmaxf(mx[rr], s);
    }
#pragma unroll
  for (int m_ = 1; m_ <= 8; m_ <<= 1)
#pragma unroll
    for (int rr = 0; rr < 4; ++rr)
      mx[rr] = fmaxf(mx[rr], __shfl_xor(mx[rr], m_));
  if (r == 0) {
#pragma unroll
    for (int rr = 0; rr < 4; ++rr) red[0][g * 4 + rr][w] = mx[rr];
  }
  __syncthreads();
  float m4[4];
#pragma unroll
  for (int rr = 0; rr < 4; ++rr)
    m4[rr] = fmaxf(fmaxf(red[0][g * 4 + rr][0], red[0][g * 4 + rr][1]),
                   fmaxf(red[0][g * 4 + rr][2], red[0][g * 4 + rr][3]));
  float sm[4] = {0.f, 0.f, 0.f, 0.f};
#pragma unroll
  for (int t = 0; t < 16; ++t)
#pragma unroll
    for (int rr = 0; rr < 4; ++rr) {
      float p = __expf(acc[t][rr] - m4[rr]);
      acc[t][rr] = p;
      sm[rr] += p;
    }
#pragma unroll
  for (int m_ = 1; m_ <= 8; m_ <<= 1)
#pragma unroll
    for (int rr = 0; rr < 4; ++rr)
      sm[rr] += __shfl_xor(sm[rr], m_);
  if (r == 0) {
#pragma unroll
    for (int rr = 0; rr < 4; ++rr) red[1][g * 4 + rr][w] = sm[rr];
  }
  __syncthreads();
  float l4[4];
#pragma unroll
  for (int rr = 0; rr < 4; ++rr)
    l4[rr] = 1.f / (red[1][g * 4 + rr][0] + red[1][g * 4 + rr][1] +
                    red[1][g * 4 + rr][2] + red[1][g * 4 + rr][3]);

  // write normalized P: fp32 -> d_out (mandatory output), bf16 -> LDS (PV input)
  float* pb = P + ((size_t)bh * 1024 + q0) * 1024 + w * 256;
#pragma unroll
  for (int t = 0; t < 16; ++t)
#pragma unroll
    for (int rr = 0; rr < 4; ++rr) {
      float p = acc[t][rr] * l4[rr];
      pb[(size_t)(g * 4 + rr) * 1024 + t * 16 + r] = p;
      Plds[(g * 4 + rr) * PSTR + w * 256 + t * 16 + r] = (bf16_t)p;
    }
  __syncthreads();

  // phase 2: PV. wave w -> d-cols [w*16, w*16+16). A from Plds, B from VT rows.
  const bf16_t* vb = VT + ((size_t)bh * 64 + w * 16) * 1024;
  f32x4 oacc = {0.f, 0.f, 0.f, 0.f};
#pragma unroll 8
  for (int kbl = 0; kbl < 32; ++kbl) {
    bf16x8 av = *reinterpret_cast<const bf16x8*>(Plds + r * PSTR + kbl * 32 + g * 8);
    bf16x8 bv = *reinterpret_cast<const bf16x8*>(vb + (size_t)r * 1024 + kbl * 32 + g * 8);
    oacc = __builtin_amdgcn_mfma_f32_16x16x32_bf16(av, bv, oacc, 0, 0, 0);
  }
#pragma unroll
  for (int rr = 0; rr < 4; ++rr)
    aout[((size_t)b * 1024 + q0 + g * 4 + rr) * 1024 + h * 64 + w * 16 + r] = (bf16_t)oacc[rr];
}

extern "C" void kernel_launch(void* const* d_in, const int* in_sizes, int n_in,
                              void* d_out, int out_size, void* d_ws, size_t ws_size,
                              hipStream_t stream) {
  const float* x      = (const float*)d_in[0];
  const float* mask   = (const float*)d_in[1];
  const float* Wq     = (const float*)d_in[2];
  const float* Wk     = (const float*)d_in[3];
  const float* Wv     = (const float*)d_in[4];
  const float* Wb     = (const float*)d_in[5];
  const float* mixing = (const float*)d_in[6];
  const float* Wd     = (const float*)d_in[7];
  const float* bd     = (const float*)d_in[8];

  char* ws = (char*)d_ws;
  bf16_t* xb   = (bf16_t*)(ws + 0);         //  8,388,608
  bf16_t* WqT  = (bf16_t*)(ws + 8388608);   //  2,097,152  } contiguous: one
  bf16_t* WkT  = (bf16_t*)(ws + 10485760);  //  2,097,152  } N=3072 B^T for
  bf16_t* WvT  = (bf16_t*)(ws + 12582912);  //  2,097,152  } fused QKV GEMM
  bf16_t* WdT  = (bf16_t*)(ws + 14680064);  //  2,097,152
  bf16_t* Qm   = (bf16_t*)(ws + 16777216);  //  8,388,608  [b,h,s,d] * mixing/8
  bf16_t* Kw   = (bf16_t*)(ws + 25165824);  //  8,388,608  [b,h,s,d]
  bf16_t* VT   = (bf16_t*)(ws + 33554432);  //  8,388,608  [b,h,d,s]
  bf16_t* aout = (bf16_t*)(ws + 41943040);  //  8,388,608  [b,s,(h,hd)]
  float*  cb   = (float*)(ws + 50331648);   //    262,144  [b,h,s]
  if (ws_size < 50593792) return;

  float* outO = (float*)d_out;        // attn_output [4,1024,1024]
  float* outP = outO + 4194304;       // attn_weights [4,16,1024,1024]

  k_cvt_bf16<<<4096, 256, 0, stream>>>(x, xb);
  k_transpose_cvt4<<<dim3(1024, 4), 256, 0, stream>>>(Wq, Wk, Wv, Wd, WqT, WkT, WvT, WdT);
  k_cbias<<<4096, 256, 0, stream>>>(x, Wb, cb);
  k_gemm128<0, 24><<<768, 256, 0, stream>>>(xb, WqT, mixing, Qm, Kw, VT, nullptr);
  k_attn_fused<<<4096, 256, 0, stream>>>(Qm, Kw, VT, cb, mask, outP, aout);
  k_gemm128<1, 8><<<256, 256, 0, stream>>>(aout, WdT, bd, nullptr, nullptr, nullptr, outO);
}